// Round 15
// baseline (2014.811 us; speedup 1.0000x reference)
//
#include <hip/hip_runtime.h>
#include <hip/hip_bf16.h>
#include <stdint.h>

#define BATCH 16384
#define DIM   2048
#define DIM2  1024

typedef __attribute__((ext_vector_type(8))) short short8;
typedef __attribute__((ext_vector_type(4))) float f32x4;

__device__ __forceinline__ ushort f2bf(float f) {
  uint32_t u = __float_as_uint(f);
  u += 0x7fffu + ((u >> 16) & 1u);   // RNE
  return (ushort)(u >> 16);
}
__device__ __forceinline__ float bf2f(ushort h) {
  return __uint_as_float(((uint32_t)h) << 16);
}

__device__ __forceinline__ void gload_lds16(const void* g, void* l) {
  __builtin_amdgcn_global_load_lds(
      (__attribute__((address_space(1))) void*)g,
      (__attribute__((address_space(3))) void*)l,
      16, 0, 0);
}

__device__ __forceinline__ f32x4 MFMA(short8 a, short8 b, f32x4 c) {
  return __builtin_amdgcn_mfma_f32_16x16x32_bf16(a, b, c, 0, 0, 0);
}

// ---- fused prep: one dispatch, 4 block roles, cos-first dispatch order ----
__device__ __forceinline__ void transW_body(const float* __restrict__ W,
                                            ushort* __restrict__ WT,
                                            int K, int N, int bx, int by) {
  __shared__ float tile[32][33];
  int t = threadIdx.x;
  int tx = t & 31, ty = t >> 5;
  int c0 = bx * 32, r0 = by * 32;
#pragma unroll
  for (int p = 0; p < 4; ++p)
    tile[ty + p * 8][tx] = W[(size_t)(r0 + ty + p * 8) * N + c0 + tx];
  __syncthreads();
#pragma unroll
  for (int p = 0; p < 4; ++p) {
    int rr = ty + p * 8;  // n offset within tile
    WT[(size_t)(c0 + rr) * K + r0 + tx] = f2bf(tile[tx][rr]);
  }
}

__global__ void __launch_bounds__(256) prep_all(const float* __restrict__ h,
                                                ushort* __restrict__ hbf,
                                                const float* __restrict__ vc,
                                                const float* __restrict__ vd,
                                                float* __restrict__ feats,
                                                const float* __restrict__ W1,
                                                ushort* __restrict__ W1T,
                                                const float* __restrict__ W2,
                                                ushort* __restrict__ W2T) {
  const int b = blockIdx.x;
  if (b < 4096) {
    // ---- cos: wave-per-row; asm keep-alive forces loads in flight ----
    const int w = threadIdx.x >> 6, l = threadIdx.x & 63;
    const int row = b * 4 + w;
    const float4* c = (const float4*)(vc + (size_t)row * DIM);
    const float4* d = (const float4*)(vd + (size_t)row * DIM);
    float4 ca[8], da[8];
#pragma unroll
    for (int j = 0; j < 8; ++j) ca[j] = c[j * 64 + l];
#pragma unroll
    for (int j = 0; j < 8; ++j) da[j] = d[j * 64 + l];
#pragma unroll
    for (int j = 0; j < 8; ++j) {
      asm volatile("" : "+v"(ca[j].x), "+v"(ca[j].y), "+v"(ca[j].z), "+v"(ca[j].w));
      asm volatile("" : "+v"(da[j].x), "+v"(da[j].y), "+v"(da[j].z), "+v"(da[j].w));
    }
    float dot = 0.f, c2 = 0.f, d2 = 0.f;
#pragma unroll
    for (int j = 0; j < 8; ++j) {
      float4 a = ca[j], bb = da[j];
      dot += a.x * bb.x + a.y * bb.y + a.z * bb.z + a.w * bb.w;
      c2  += a.x * a.x + a.y * a.y + a.z * a.z + a.w * a.w;
      d2  += bb.x * bb.x + bb.y * bb.y + bb.z * bb.z + bb.w * bb.w;
    }
#pragma unroll
    for (int off = 32; off >= 1; off >>= 1) {
      dot += __shfl_xor(dot, off, 64);
      c2  += __shfl_xor(c2, off, 64);
      d2  += __shfl_xor(d2, off, 64);
    }
    if (l == 0) {
      float nc = fmaxf(sqrtf(c2), 1e-12f);
      float nd = fmaxf(sqrtf(d2), 1e-12f);
      float align = dot / (nc * nd);
      float dv = 1.f - align;
      feats[row] = align;
      feats[BATCH + row] = dv;
      feats[2 * BATCH + row] = dv * dv;
    }
  } else if (b < 12288) {
    // ---- cvt: 4-deep unrolled grid-stride streams ----
    const int i0 = (b - 4096) * 256 + threadIdx.x;
    const int S = 8192 * 256;  // stride in float4 units
    const float4* p = (const float4*)h;
    uint2* o = (uint2*)hbf;
    float4 f[4];
#pragma unroll
    for (int j = 0; j < 4; ++j) f[j] = p[i0 + j * S];
#pragma unroll
    for (int j = 0; j < 4; ++j) {
      uint2 u;
      u.x = (uint32_t)f2bf(f[j].x) | ((uint32_t)f2bf(f[j].y) << 16);
      u.y = (uint32_t)f2bf(f[j].z) | ((uint32_t)f2bf(f[j].w) << 16);
      o[i0 + j * S] = u;
    }
  } else if (b < 16384) {
    const int bb = b - 12288;
    transW_body(W1, W1T, DIM, DIM, bb & 63, bb >> 6);
  } else {
    const int bb = b - 16384;
    transW_body(W2, W2T, DIM, DIM2, bb & 31, bb >> 5);
  }
}

// ------- 256x256 bf16 MFMA GEMM, 4-slot 64KB ring, 2 blocks/CU -----------
// 8 waves (2M x 4N), 128x64/wave, 16x16x32 MFMA, XOR swizzle (rule #21),
// XCD-chunked block map. Ring: 4 slots of 16KB = [slot(kh parity)][{A,B}].
// Per K-tile: p0 stages THIS tile's kh1->slot1 (read p2, 2-phase lead);
// p2 stages NEXT tile's kh0->slot0 (read next p0, 2-phase lead). Restage
// always targets a slot whose last reader is behind the previous odd-phase
// barrier. vmcnt(0)+barrier at odd-phase closes only. 64KB LDS -> 2 blocks
// co-resident (4 waves/SIMD) hide each other's stalls.
// MODE 1: C = relu(A*BT^T + rank3 + bias), bf16 out.
// MODE 2: fused head -- per-row partials of relu(acc+b2).Wr -> partial[].
template <int MODE, int N>
__global__ void __launch_bounds__(512, 4) gemm256(const ushort* __restrict__ A,
                                                  const ushort* __restrict__ BT,
                                                  ushort* __restrict__ C,
                                                  const float* __restrict__ feats,
                                                  const float* __restrict__ wex,
                                                  const float* __restrict__ bias,
                                                  const float* __restrict__ Wr,
                                                  float* __restrict__ partial) {
  constexpr int K = 2048;
  constexpr int NH = K / 32;   // 64 K-halves, 32 K-tiles
  __shared__ __align__(16) char lds[65536];
  const int tid = threadIdx.x;
  const int l = tid & 63, w = tid >> 6;
  const int wr = w >> 2, wc = w & 3;
  const int l4 = l & 15, lhi = l >> 4;

  constexpr int GX = N / 256;
  const int bid = blockIdx.x;
  const int xcd = bid & 7;
  const int s = bid >> 3;
  const int tx = s % GX;
  const int ty = xcd * 8 + s / GX;
  const size_t rowBase = (size_t)ty * 256;
  const int colBase = tx * 256;

  // ds_read offsets (within a 16KB slot)
  const int swz = (l4 & 7) << 4;
  const int aoffBase = l4 * 128 + ((wr * 64 + lhi * 16) ^ swz);
  const int boffBase = ((wc & 1) * 64 + l4) * 128 + (((wc >> 1) * 64 + lhi * 16) ^ swz);

  // stage source pointers: LDS offset o = c*8192 + tid*16 decodes as
  // lds-row r = o>>7, byte-in-row b0 = o&127; source = inverse-swizzle of b0.
  // K-half h occupies byte offset h*64 within each global row.
  const char* pAs[2];
  const char* pBs[2];
#pragma unroll
  for (int c = 0; c < 2; ++c) {
    int o = c * 8192 + tid * 16;
    int r = o >> 7, b0 = o & 127;
    int bsw = b0 ^ ((r & 7) << 4);
    int hb = bsw >> 6, cb = bsw & 63;
    pAs[c] = (const char*)A + (rowBase + hb * 128 + r) * (2 * K) + cb;
    pBs[c] = (const char*)BT + ((size_t)colBase + hb * 128 + r) * (2 * K) + cb;
  }
  const int ldso0 = w * 1024;
  const int ldso1 = 8192 + w * 1024;

#define STAGE(h, slot, M)                                                    \
  do {                                                                       \
    char* dst_ = lds + (slot) * 32768 + (M) * 16384;                         \
    const char* s0_ = ((M) ? pBs[0] : pAs[0]) + (h) * 64;                    \
    const char* s1_ = ((M) ? pBs[1] : pAs[1]) + (h) * 64;                    \
    gload_lds16(s0_, dst_ + ldso0);                                          \
    gload_lds16(s1_, dst_ + ldso1);                                          \
    asm volatile("" ::: "memory");                                           \
  } while (0)

#define LOADA(q, slot)                                                       \
  do {                                                                       \
    const char* sb_ = lds + (slot) * 32768;                                  \
    aq[0] = *(const short8*)(sb_ + ((q) * 4 + 0) * 2048 + aoffBase);         \
    aq[1] = *(const short8*)(sb_ + ((q) * 4 + 1) * 2048 + aoffBase);         \
    aq[2] = *(const short8*)(sb_ + ((q) * 4 + 2) * 2048 + aoffBase);         \
    aq[3] = *(const short8*)(sb_ + ((q) * 4 + 3) * 2048 + aoffBase);         \
  } while (0)

#define LOADB(slot)                                                          \
  do {                                                                       \
    const char* sb_ = lds + (slot) * 32768 + 16384;                          \
    bq[0] = *(const short8*)(sb_ + 0 * 2048 + boffBase);                     \
    bq[1] = *(const short8*)(sb_ + 1 * 2048 + boffBase);                     \
    bq[2] = *(const short8*)(sb_ + 2 * 2048 + boffBase);                     \
    bq[3] = *(const short8*)(sb_ + 3 * 2048 + boffBase);                     \
  } while (0)

#define MF(q)                                                                \
  do {                                                                       \
    _Pragma("unroll") for (int j_ = 0; j_ < 4; ++j_)                         \
        _Pragma("unroll") for (int n_ = 0; n_ < 4; ++n_)                     \
            acc[(q) * 4 + j_][n_] = MFMA(aq[j_], bq[n_], acc[(q) * 4 + j_][n_]); \
  } while (0)

#define BAR()     __builtin_amdgcn_s_barrier()
#define MEMF()    asm volatile("" ::: "memory")
#define VM0()     asm volatile("s_waitcnt vmcnt(0)" ::: "memory")
#define PRIO(x)   __builtin_amdgcn_s_setprio(x)

  f32x4 acc[8][4];
#pragma unroll
  for (int i = 0; i < 8; ++i)
#pragma unroll
    for (int j = 0; j < 4; ++j) acc[i][j] = (f32x4){0.f, 0.f, 0.f, 0.f};

  // prologue: stage K-half 0 into slot0 (A+B), drain, publish
  STAGE(0, 0, 0);
  STAGE(0, 0, 1);
  VM0();
  BAR();
  MEMF();

  for (int I = 0; I < NH / 2; ++I) {
    const int h1 = 2 * I + 1;                        // staged p0, read p2/p3
    const int e  = (2 * I + 2 < NH) ? 2 * I + 2 : 0; // staged p2, read next p0/p1
    short8 aq[4], bq[4];
    // ---- p0: kh0, q0 ----
    LOADB(0);
    LOADA(0, 0);
    STAGE(h1, 1, 0);
    STAGE(h1, 1, 1);
    PRIO(1); MF(0); PRIO(0);
    MEMF();
    // ---- p1: kh0, q1 ----
    LOADA(1, 0);
    PRIO(1); MF(1); PRIO(0);
    VM0();
    MEMF(); BAR(); MEMF();
    // ---- p2: kh1, q0 ----
    LOADB(1);
    LOADA(0, 1);
    STAGE(e, 0, 0);
    STAGE(e, 0, 1);
    PRIO(1); MF(0); PRIO(0);
    MEMF();
    // ---- p3: kh1, q1 ----
    LOADA(1, 1);
    PRIO(1); MF(1); PRIO(0);
    VM0();
    MEMF(); BAR(); MEMF();
  }

  const int lhi4 = lhi * 4;
  if (MODE == 1) {
    // epilogue: C/D map col=lane&15, row=(lane>>4)*4+reg  [m89/m91 verified]
    int ccv[4];
    float bb[4], wa[4], wb2[4], wc3[4];
#pragma unroll
    for (int n = 0; n < 4; ++n) {
      int cc = colBase + wc * 64 + n * 16 + l4;
      ccv[n] = cc;
      bb[n] = bias[cc];
      wa[n] = wex[cc]; wb2[n] = wex[2048 + cc]; wc3[n] = wex[4096 + cc];
    }
#pragma unroll
    for (int m = 0; m < 8; ++m) {
#pragma unroll
      for (int r = 0; r < 4; ++r) {
        size_t rr = rowBase + wr * 128 + m * 16 + lhi4 + r;
        float f1 = feats[rr], f2 = feats[BATCH + rr], f3 = feats[2 * BATCH + rr];
#pragma unroll
        for (int n = 0; n < 4; ++n) {
          float v = acc[m][n][r] + bb[n] + f1 * wa[n] + f2 * wb2[n] + f3 * wc3[n];
          v = fmaxf(v, 0.f);
          C[rr * N + ccv[n]] = f2bf(v);
        }
      }
    }
  } else {
    // fused head: per-row partial of relu(acc + b2) . Wr over this wave's
    // 64 cols; l4-group shfl reduction (lanes sharing a row); one fp32 store.
    float bb[4], wrv[4];
#pragma unroll
    for (int n = 0; n < 4; ++n) {
      int cc = colBase + wc * 64 + n * 16 + l4;
      bb[n] = bias[cc];
      wrv[n] = Wr[cc];
    }
#pragma unroll
    for (int m = 0; m < 8; ++m) {
#pragma unroll
      for (int r = 0; r < 4; ++r) {
        size_t rr = rowBase + wr * 128 + m * 16 + lhi4 + r;
        float p = 0.f;
#pragma unroll
        for (int n = 0; n < 4; ++n)
          p += fmaxf(acc[m][n][r] + bb[n], 0.f) * wrv[n];
        p += __shfl_xor(p, 1, 64);
        p += __shfl_xor(p, 2, 64);
        p += __shfl_xor(p, 4, 64);
        p += __shfl_xor(p, 8, 64);
        if (l4 == 0) partial[rr * 16 + tx * 4 + wc] = p;
      }
    }
  }
#undef STAGE
#undef LOADA
#undef LOADB
#undef MF
#undef BAR
#undef MEMF
#undef VM0
#undef PRIO
}

// ---------------- final: sum 16 partials per row + sigmoid ----------------
__global__ void __launch_bounds__(256) head2_kernel(const float* __restrict__ partial,
                                                    const float* __restrict__ br,
                                                    float* __restrict__ out) {
  int row = blockIdx.x * 256 + threadIdx.x;
  const float4* p = (const float4*)(partial + (size_t)row * 16);
  float4 a = p[0], b = p[1], c = p[2], d = p[3];
  float s = a.x + a.y + a.z + a.w + b.x + b.y + b.z + b.w +
            c.x + c.y + c.z + c.w + d.x + d.y + d.z + d.w + br[0];
  out[row] = 1.f / (1.f + expf(-s));
}

extern "C" void kernel_launch(void* const* d_in, const int* in_sizes, int n_in,
                              void* d_out, int out_size, void* d_ws, size_t ws_size,
                              hipStream_t stream) {
  const float* h_final = (const float*)d_in[0];
  const float* v_claim = (const float*)d_in[1];
  const float* v_doc   = (const float*)d_in[2];
  const float* W1      = (const float*)d_in[3];
  const float* b1      = (const float*)d_in[4];
  const float* W2      = (const float*)d_in[5];
  const float* b2      = (const float*)d_in[6];
  const float* Wr      = (const float*)d_in[7];
  const float* br      = (const float*)d_in[8];
  float* out = (float*)d_out;

  char* ws = (char*)d_ws;
  ushort* Abf   = (ushort*)ws;                           // 67,108,864 B
  ushort* Hbf   = (ushort*)(ws + 67108864);              // 67,108,864 B
  ushort* W1T   = (ushort*)(ws + 134217728);             //  8,388,608 B
  ushort* W2T   = (ushort*)(ws + 142606336);             //  4,194,304 B
  float*  feats = (float*)(ws + 146800640);              //    196,608 B
  float*  partial = (float*)(ws + 147000320);            // 1,048,576 B

  prep_all<<<18432, 256, 0, stream>>>(h_final, Abf, v_claim, v_doc, feats,
                                      W1, W1T, W2, W2T);

  gemm256<1, DIM><<<(DIM / 256) * (BATCH / 256), 512, 0, stream>>>(
      Abf, W1T, Hbf, feats, W1 + (size_t)2048 * 2048, b1, nullptr, nullptr);
  gemm256<2, DIM2><<<(DIM2 / 256) * (BATCH / 256), 512, 0, stream>>>(
      Hbf, W2T, nullptr, nullptr, nullptr, b2, Wr, partial);

  head2_kernel<<<BATCH / 256, 256, 0, stream>>>(partial, br, out);
}

// Round 16
// 279.404 us; speedup vs baseline: 7.2111x; 7.2111x over previous
//
#include <hip/hip_runtime.h>
#include <hip/hip_bf16.h>
#include <stdint.h>

#define BATCH 16384
#define DIM   2048
#define DIM2  1024

typedef __attribute__((ext_vector_type(8))) short short8;
typedef __attribute__((ext_vector_type(4))) float f32x4;

__device__ __forceinline__ ushort f2bf(float f) {
  uint32_t u = __float_as_uint(f);
  u += 0x7fffu + ((u >> 16) & 1u);   // RNE
  return (ushort)(u >> 16);
}
__device__ __forceinline__ float bf2f(ushort h) {
  return __uint_as_float(((uint32_t)h) << 16);
}

__device__ __forceinline__ void gload_lds16(const void* g, void* l) {
  __builtin_amdgcn_global_load_lds(
      (__attribute__((address_space(1))) void*)g,
      (__attribute__((address_space(3))) void*)l,
      16, 0, 0);
}

__device__ __forceinline__ f32x4 MFMA(short8 a, short8 b, f32x4 c) {
  return __builtin_amdgcn_mfma_f32_16x16x32_bf16(a, b, c, 0, 0, 0);
}

// ---- fused prep: one dispatch, 4 block roles, cos-first dispatch order ----
__device__ __forceinline__ void transW_body(const float* __restrict__ W,
                                            ushort* __restrict__ WT,
                                            int K, int N, int bx, int by) {
  __shared__ float tile[32][33];
  int t = threadIdx.x;
  int tx = t & 31, ty = t >> 5;
  int c0 = bx * 32, r0 = by * 32;
#pragma unroll
  for (int p = 0; p < 4; ++p)
    tile[ty + p * 8][tx] = W[(size_t)(r0 + ty + p * 8) * N + c0 + tx];
  __syncthreads();
#pragma unroll
  for (int p = 0; p < 4; ++p) {
    int rr = ty + p * 8;  // n offset within tile
    WT[(size_t)(c0 + rr) * K + r0 + tx] = f2bf(tile[tx][rr]);
  }
}

__global__ void __launch_bounds__(256) prep_all(const float* __restrict__ h,
                                                ushort* __restrict__ hbf,
                                                const float* __restrict__ vc,
                                                const float* __restrict__ vd,
                                                float* __restrict__ feats,
                                                const float* __restrict__ W1,
                                                ushort* __restrict__ W1T,
                                                const float* __restrict__ W2,
                                                ushort* __restrict__ W2T) {
  const int b = blockIdx.x;
  if (b < 4096) {
    // ---- cos: wave-per-row; asm keep-alive forces loads in flight ----
    const int w = threadIdx.x >> 6, l = threadIdx.x & 63;
    const int row = b * 4 + w;
    const float4* c = (const float4*)(vc + (size_t)row * DIM);
    const float4* d = (const float4*)(vd + (size_t)row * DIM);
    float4 ca[8], da[8];
#pragma unroll
    for (int j = 0; j < 8; ++j) ca[j] = c[j * 64 + l];
#pragma unroll
    for (int j = 0; j < 8; ++j) da[j] = d[j * 64 + l];
#pragma unroll
    for (int j = 0; j < 8; ++j) {
      asm volatile("" : "+v"(ca[j].x), "+v"(ca[j].y), "+v"(ca[j].z), "+v"(ca[j].w));
      asm volatile("" : "+v"(da[j].x), "+v"(da[j].y), "+v"(da[j].z), "+v"(da[j].w));
    }
    float dot = 0.f, c2 = 0.f, d2 = 0.f;
#pragma unroll
    for (int j = 0; j < 8; ++j) {
      float4 a = ca[j], bb = da[j];
      dot += a.x * bb.x + a.y * bb.y + a.z * bb.z + a.w * bb.w;
      c2  += a.x * a.x + a.y * a.y + a.z * a.z + a.w * a.w;
      d2  += bb.x * bb.x + bb.y * bb.y + bb.z * bb.z + bb.w * bb.w;
    }
#pragma unroll
    for (int off = 32; off >= 1; off >>= 1) {
      dot += __shfl_xor(dot, off, 64);
      c2  += __shfl_xor(c2, off, 64);
      d2  += __shfl_xor(d2, off, 64);
    }
    if (l == 0) {
      float nc = fmaxf(sqrtf(c2), 1e-12f);
      float nd = fmaxf(sqrtf(d2), 1e-12f);
      float align = dot / (nc * nd);
      float dv = 1.f - align;
      feats[row] = align;
      feats[BATCH + row] = dv;
      feats[2 * BATCH + row] = dv * dv;
    }
  } else if (b < 12288) {
    // ---- cvt: 4-deep unrolled grid-stride streams ----
    const int i0 = (b - 4096) * 256 + threadIdx.x;
    const int S = 8192 * 256;  // stride in float4 units
    const float4* p = (const float4*)h;
    uint2* o = (uint2*)hbf;
    float4 f[4];
#pragma unroll
    for (int j = 0; j < 4; ++j) f[j] = p[i0 + j * S];
#pragma unroll
    for (int j = 0; j < 4; ++j) {
      uint2 u;
      u.x = (uint32_t)f2bf(f[j].x) | ((uint32_t)f2bf(f[j].y) << 16);
      u.y = (uint32_t)f2bf(f[j].z) | ((uint32_t)f2bf(f[j].w) << 16);
      o[i0 + j * S] = u;
    }
  } else if (b < 16384) {
    const int bb = b - 12288;
    transW_body(W1, W1T, DIM, DIM, bb & 63, bb >> 6);
  } else {
    const int bb = b - 16384;
    transW_body(W2, W2T, DIM, DIM2, bb & 31, bb >> 5);
  }
}

// ------- 256x256 bf16 MFMA GEMM, 4-slot 64KB ring, 2 blocks/CU -----------
// 8 waves (2M x 4N), 128x64/wave, 16x16x32 MFMA, XOR swizzle (rule #21),
// XCD-chunked block map. Ring: 4 slots of 16KB = [slot(kh parity)][{A,B}].
// Per K-tile: p0 stages THIS tile's kh1->slot1 (read p2, 2-phase lead);
// p2 stages NEXT tile's kh0->slot0 (read next p0, 2-phase lead). Restage
// always targets a slot whose last reader is behind the previous odd-phase
// barrier. vmcnt(0)+barrier at odd-phase closes only. 64KB LDS -> 2 blocks
// co-resident; launch_bounds(512,2) caps unified VGPR+AGPR at 256 (>=~248
// needed -> no spill; r15's (512,4) cap of 128 spilled the accumulator).
// MODE 1: C = relu(A*BT^T + rank3 + bias), bf16 out.
// MODE 2: fused head -- per-row partials of relu(acc+b2).Wr -> partial[].
template <int MODE, int N>
__global__ void __launch_bounds__(512, 2) gemm256(const ushort* __restrict__ A,
                                                  const ushort* __restrict__ BT,
                                                  ushort* __restrict__ C,
                                                  const float* __restrict__ feats,
                                                  const float* __restrict__ wex,
                                                  const float* __restrict__ bias,
                                                  const float* __restrict__ Wr,
                                                  float* __restrict__ partial) {
  constexpr int K = 2048;
  constexpr int NH = K / 32;   // 64 K-halves, 32 K-tiles
  __shared__ __align__(16) char lds[65536];
  const int tid = threadIdx.x;
  const int l = tid & 63, w = tid >> 6;
  const int wr = w >> 2, wc = w & 3;
  const int l4 = l & 15, lhi = l >> 4;

  constexpr int GX = N / 256;
  const int bid = blockIdx.x;
  const int xcd = bid & 7;
  const int s = bid >> 3;
  const int tx = s % GX;
  const int ty = xcd * 8 + s / GX;
  const size_t rowBase = (size_t)ty * 256;
  const int colBase = tx * 256;

  // ds_read offsets (within a 16KB slot)
  const int swz = (l4 & 7) << 4;
  const int aoffBase = l4 * 128 + ((wr * 64 + lhi * 16) ^ swz);
  const int boffBase = ((wc & 1) * 64 + l4) * 128 + (((wc >> 1) * 64 + lhi * 16) ^ swz);

  // stage source pointers: LDS offset o = c*8192 + tid*16 decodes as
  // lds-row r = o>>7, byte-in-row b0 = o&127; source = inverse-swizzle of b0.
  // K-half h occupies byte offset h*64 within each global row.
  const char* pAs[2];
  const char* pBs[2];
#pragma unroll
  for (int c = 0; c < 2; ++c) {
    int o = c * 8192 + tid * 16;
    int r = o >> 7, b0 = o & 127;
    int bsw = b0 ^ ((r & 7) << 4);
    int hb = bsw >> 6, cb = bsw & 63;
    pAs[c] = (const char*)A + (rowBase + hb * 128 + r) * (2 * K) + cb;
    pBs[c] = (const char*)BT + ((size_t)colBase + hb * 128 + r) * (2 * K) + cb;
  }
  const int ldso0 = w * 1024;
  const int ldso1 = 8192 + w * 1024;

#define STAGE(h, slot, M)                                                    \
  do {                                                                       \
    char* dst_ = lds + (slot) * 32768 + (M) * 16384;                         \
    const char* s0_ = ((M) ? pBs[0] : pAs[0]) + (h) * 64;                    \
    const char* s1_ = ((M) ? pBs[1] : pAs[1]) + (h) * 64;                    \
    gload_lds16(s0_, dst_ + ldso0);                                          \
    gload_lds16(s1_, dst_ + ldso1);                                          \
    asm volatile("" ::: "memory");                                           \
  } while (0)

#define LOADA(q, slot)                                                       \
  do {                                                                       \
    const char* sb_ = lds + (slot) * 32768;                                  \
    aq[0] = *(const short8*)(sb_ + ((q) * 4 + 0) * 2048 + aoffBase);         \
    aq[1] = *(const short8*)(sb_ + ((q) * 4 + 1) * 2048 + aoffBase);         \
    aq[2] = *(const short8*)(sb_ + ((q) * 4 + 2) * 2048 + aoffBase);         \
    aq[3] = *(const short8*)(sb_ + ((q) * 4 + 3) * 2048 + aoffBase);         \
  } while (0)

#define LOADB(slot)                                                          \
  do {                                                                       \
    const char* sb_ = lds + (slot) * 32768 + 16384;                          \
    bq[0] = *(const short8*)(sb_ + 0 * 2048 + boffBase);                     \
    bq[1] = *(const short8*)(sb_ + 1 * 2048 + boffBase);                     \
    bq[2] = *(const short8*)(sb_ + 2 * 2048 + boffBase);                     \
    bq[3] = *(const short8*)(sb_ + 3 * 2048 + boffBase);                     \
  } while (0)

#define MF(q)                                                                \
  do {                                                                       \
    _Pragma("unroll") for (int j_ = 0; j_ < 4; ++j_)                         \
        _Pragma("unroll") for (int n_ = 0; n_ < 4; ++n_)                     \
            acc[(q) * 4 + j_][n_] = MFMA(aq[j_], bq[n_], acc[(q) * 4 + j_][n_]); \
  } while (0)

#define BAR()     __builtin_amdgcn_s_barrier()
#define MEMF()    asm volatile("" ::: "memory")
#define VM0()     asm volatile("s_waitcnt vmcnt(0)" ::: "memory")
#define PRIO(x)   __builtin_amdgcn_s_setprio(x)

  f32x4 acc[8][4];
#pragma unroll
  for (int i = 0; i < 8; ++i)
#pragma unroll
    for (int j = 0; j < 4; ++j) acc[i][j] = (f32x4){0.f, 0.f, 0.f, 0.f};

  // prologue: stage K-half 0 into slot0 (A+B), drain, publish
  STAGE(0, 0, 0);
  STAGE(0, 0, 1);
  VM0();
  BAR();
  MEMF();

  for (int I = 0; I < NH / 2; ++I) {
    const int h1 = 2 * I + 1;                        // staged p0, read p2/p3
    const int e  = (2 * I + 2 < NH) ? 2 * I + 2 : 0; // staged p2, read next p0/p1
    short8 aq[4], bq[4];
    // ---- p0: kh0, q0 ----
    LOADB(0);
    LOADA(0, 0);
    STAGE(h1, 1, 0);
    STAGE(h1, 1, 1);
    PRIO(1); MF(0); PRIO(0);
    MEMF();
    // ---- p1: kh0, q1 ----
    LOADA(1, 0);
    PRIO(1); MF(1); PRIO(0);
    VM0();
    MEMF(); BAR(); MEMF();
    // ---- p2: kh1, q0 ----
    LOADB(1);
    LOADA(0, 1);
    STAGE(e, 0, 0);
    STAGE(e, 0, 1);
    PRIO(1); MF(0); PRIO(0);
    MEMF();
    // ---- p3: kh1, q1 ----
    LOADA(1, 1);
    PRIO(1); MF(1); PRIO(0);
    VM0();
    MEMF(); BAR(); MEMF();
  }

  const int lhi4 = lhi * 4;
  if (MODE == 1) {
    // epilogue: C/D map col=lane&15, row=(lane>>4)*4+reg  [m89/m91 verified]
    int ccv[4];
    float bb[4], wa[4], wb2[4], wc3[4];
#pragma unroll
    for (int n = 0; n < 4; ++n) {
      int cc = colBase + wc * 64 + n * 16 + l4;
      ccv[n] = cc;
      bb[n] = bias[cc];
      wa[n] = wex[cc]; wb2[n] = wex[2048 + cc]; wc3[n] = wex[4096 + cc];
    }
#pragma unroll
    for (int m = 0; m < 8; ++m) {
#pragma unroll
      for (int r = 0; r < 4; ++r) {
        size_t rr = rowBase + wr * 128 + m * 16 + lhi4 + r;
        float f1 = feats[rr], f2 = feats[BATCH + rr], f3 = feats[2 * BATCH + rr];
#pragma unroll
        for (int n = 0; n < 4; ++n) {
          float v = acc[m][n][r] + bb[n] + f1 * wa[n] + f2 * wb2[n] + f3 * wc3[n];
          v = fmaxf(v, 0.f);
          C[rr * N + ccv[n]] = f2bf(v);
        }
      }
    }
  } else {
    // fused head: per-row partial of relu(acc + b2) . Wr over this wave's
    // 64 cols; l4-group shfl reduction (lanes sharing a row); one fp32 store.
    float bb[4], wrv[4];
#pragma unroll
    for (int n = 0; n < 4; ++n) {
      int cc = colBase + wc * 64 + n * 16 + l4;
      bb[n] = bias[cc];
      wrv[n] = Wr[cc];
    }
#pragma unroll
    for (int m = 0; m < 8; ++m) {
#pragma unroll
      for (int r = 0; r < 4; ++r) {
        size_t rr = rowBase + wr * 128 + m * 16 + lhi4 + r;
        float p = 0.f;
#pragma unroll
        for (int n = 0; n < 4; ++n)
          p += fmaxf(acc[m][n][r] + bb[n], 0.f) * wrv[n];
        p += __shfl_xor(p, 1, 64);
        p += __shfl_xor(p, 2, 64);
        p += __shfl_xor(p, 4, 64);
        p += __shfl_xor(p, 8, 64);
        if (l4 == 0) partial[rr * 16 + tx * 4 + wc] = p;
      }
    }
  }
#undef STAGE
#undef LOADA
#undef LOADB
#undef MF
#undef BAR
#undef MEMF
#undef VM0
#undef PRIO
}

// ---------------- final: sum 16 partials per row + sigmoid ----------------
__global__ void __launch_bounds__(256) head2_kernel(const float* __restrict__ partial,
                                                    const float* __restrict__ br,
                                                    float* __restrict__ out) {
  int row = blockIdx.x * 256 + threadIdx.x;
  const float4* p = (const float4*)(partial + (size_t)row * 16);
  float4 a = p[0], b = p[1], c = p[2], d = p[3];
  float s = a.x + a.y + a.z + a.w + b.x + b.y + b.z + b.w +
            c.x + c.y + c.z + c.w + d.x + d.y + d.z + d.w + br[0];
  out[row] = 1.f / (1.f + expf(-s));
}

extern "C" void kernel_launch(void* const* d_in, const int* in_sizes, int n_in,
                              void* d_out, int out_size, void* d_ws, size_t ws_size,
                              hipStream_t stream) {
  const float* h_final = (const float*)d_in[0];
  const float* v_claim = (const float*)d_in[1];
  const float* v_doc   = (const float*)d_in[2];
  const float* W1      = (const float*)d_in[3];
  const float* b1      = (const float*)d_in[4];
  const float* W2      = (const float*)d_in[5];
  const float* b2      = (const float*)d_in[6];
  const float* Wr      = (const float*)d_in[7];
  const float* br      = (const float*)d_in[8];
  float* out = (float*)d_out;

  char* ws = (char*)d_ws;
  ushort* Abf   = (ushort*)ws;                           // 67,108,864 B
  ushort* Hbf   = (ushort*)(ws + 67108864);              // 67,108,864 B
  ushort* W1T   = (ushort*)(ws + 134217728);             //  8,388,608 B
  ushort* W2T   = (ushort*)(ws + 142606336);             //  4,194,304 B
  float*  feats = (float*)(ws + 146800640);              //    196,608 B
  float*  partial = (float*)(ws + 147000320);            // 1,048,576 B

  prep_all<<<18432, 256, 0, stream>>>(h_final, Abf, v_claim, v_doc, feats,
                                      W1, W1T, W2, W2T);

  gemm256<1, DIM><<<(DIM / 256) * (BATCH / 256), 512, 0, stream>>>(
      Abf, W1T, Hbf, feats, W1 + (size_t)2048 * 2048, b1, nullptr, nullptr);
  gemm256<2, DIM2><<<(DIM2 / 256) * (BATCH / 256), 512, 0, stream>>>(
      Hbf, W2T, nullptr, nullptr, nullptr, b2, Wr, partial);

  head2_kernel<<<BATCH / 256, 256, 0, stream>>>(partial, br, out);
}

// Round 17
// 271.821 us; speedup vs baseline: 7.4123x; 1.0279x over previous
//
#include <hip/hip_runtime.h>
#include <hip/hip_bf16.h>
#include <stdint.h>

#define BATCH 16384
#define DIM   2048
#define DIM2  1024

typedef __attribute__((ext_vector_type(8))) short short8;
typedef __attribute__((ext_vector_type(4))) float f32x4;

__device__ __forceinline__ ushort f2bf(float f) {
  uint32_t u = __float_as_uint(f);
  u += 0x7fffu + ((u >> 16) & 1u);   // RNE
  return (ushort)(u >> 16);
}
__device__ __forceinline__ float bf2f(ushort h) {
  return __uint_as_float(((uint32_t)h) << 16);
}

__device__ __forceinline__ void gload_lds16(const void* g, void* l) {
  __builtin_amdgcn_global_load_lds(
      (__attribute__((address_space(1))) void*)g,
      (__attribute__((address_space(3))) void*)l,
      16, 0, 0);
}

__device__ __forceinline__ f32x4 MFMA(short8 a, short8 b, f32x4 c) {
  return __builtin_amdgcn_mfma_f32_16x16x32_bf16(a, b, c, 0, 0, 0);
}

// ---- fused prep: one dispatch, 4 block roles, cos-first dispatch order ----
__device__ __forceinline__ void transW_body(const float* __restrict__ W,
                                            ushort* __restrict__ WT,
                                            int K, int N, int bx, int by) {
  __shared__ float tile[32][33];
  int t = threadIdx.x;
  int tx = t & 31, ty = t >> 5;
  int c0 = bx * 32, r0 = by * 32;
#pragma unroll
  for (int p = 0; p < 4; ++p)
    tile[ty + p * 8][tx] = W[(size_t)(r0 + ty + p * 8) * N + c0 + tx];
  __syncthreads();
#pragma unroll
  for (int p = 0; p < 4; ++p) {
    int rr = ty + p * 8;  // n offset within tile
    WT[(size_t)(c0 + rr) * K + r0 + tx] = f2bf(tile[tx][rr]);
  }
}

__global__ void __launch_bounds__(256) prep_all(const float* __restrict__ h,
                                                ushort* __restrict__ hbf,
                                                const float* __restrict__ vc,
                                                const float* __restrict__ vd,
                                                float* __restrict__ feats,
                                                const float* __restrict__ W1,
                                                ushort* __restrict__ W1T,
                                                const float* __restrict__ W2,
                                                ushort* __restrict__ W2T) {
  const int b = blockIdx.x;
  if (b < 4096) {
    // ---- cos: wave-per-row; asm keep-alive forces loads in flight ----
    const int w = threadIdx.x >> 6, l = threadIdx.x & 63;
    const int row = b * 4 + w;
    const float4* c = (const float4*)(vc + (size_t)row * DIM);
    const float4* d = (const float4*)(vd + (size_t)row * DIM);
    float4 ca[8], da[8];
#pragma unroll
    for (int j = 0; j < 8; ++j) ca[j] = c[j * 64 + l];
#pragma unroll
    for (int j = 0; j < 8; ++j) da[j] = d[j * 64 + l];
#pragma unroll
    for (int j = 0; j < 8; ++j) {
      asm volatile("" : "+v"(ca[j].x), "+v"(ca[j].y), "+v"(ca[j].z), "+v"(ca[j].w));
      asm volatile("" : "+v"(da[j].x), "+v"(da[j].y), "+v"(da[j].z), "+v"(da[j].w));
    }
    float dot = 0.f, c2 = 0.f, d2 = 0.f;
#pragma unroll
    for (int j = 0; j < 8; ++j) {
      float4 a = ca[j], bb = da[j];
      dot += a.x * bb.x + a.y * bb.y + a.z * bb.z + a.w * bb.w;
      c2  += a.x * a.x + a.y * a.y + a.z * a.z + a.w * a.w;
      d2  += bb.x * bb.x + bb.y * bb.y + bb.z * bb.z + bb.w * bb.w;
    }
#pragma unroll
    for (int off = 32; off >= 1; off >>= 1) {
      dot += __shfl_xor(dot, off, 64);
      c2  += __shfl_xor(c2, off, 64);
      d2  += __shfl_xor(d2, off, 64);
    }
    if (l == 0) {
      float nc = fmaxf(sqrtf(c2), 1e-12f);
      float nd = fmaxf(sqrtf(d2), 1e-12f);
      float align = dot / (nc * nd);
      float dv = 1.f - align;
      feats[row] = align;
      feats[BATCH + row] = dv;
      feats[2 * BATCH + row] = dv * dv;
    }
  } else if (b < 12288) {
    // ---- cvt: 4-deep unrolled grid-stride streams ----
    const int i0 = (b - 4096) * 256 + threadIdx.x;
    const int S = 8192 * 256;  // stride in float4 units
    const float4* p = (const float4*)h;
    uint2* o = (uint2*)hbf;
    float4 f[4];
#pragma unroll
    for (int j = 0; j < 4; ++j) f[j] = p[i0 + j * S];
#pragma unroll
    for (int j = 0; j < 4; ++j) {
      uint2 u;
      u.x = (uint32_t)f2bf(f[j].x) | ((uint32_t)f2bf(f[j].y) << 16);
      u.y = (uint32_t)f2bf(f[j].z) | ((uint32_t)f2bf(f[j].w) << 16);
      o[i0 + j * S] = u;
    }
  } else if (b < 16384) {
    const int bb = b - 12288;
    transW_body(W1, W1T, DIM, DIM, bb & 63, bb >> 6);
  } else {
    const int bb = b - 16384;
    transW_body(W2, W2T, DIM, DIM2, bb & 31, bb >> 5);
  }
}

// ---------------- 256x256 bf16 MFMA GEMM, 8-phase K-half slot ring ---------
// Best-measured structure (r13/r14): 8 waves (2M x 4N), 128x64/wave, 16x16x32
// MFMA, K-half slots of 16KB, XOR swizzle (rule #21), one slot staged per
// phase (read 6 phases later), VM8+BAR at odd-phase closes only.
// MODE 1: C = relu(A*BT^T + rank3 + bias), bf16 out.
// MODE 2: fused head -- no C write; per-row partials of
//         relu(acc+b2) . Wr  ->  partial[row*16 + tx*4 + wc].
template <int MODE, int N>
__global__ void __launch_bounds__(512, 1) gemm256(const ushort* __restrict__ A,
                                                  const ushort* __restrict__ BT,
                                                  ushort* __restrict__ C,
                                                  const float* __restrict__ feats,
                                                  const float* __restrict__ wex,
                                                  const float* __restrict__ bias,
                                                  const float* __restrict__ Wr,
                                                  float* __restrict__ partial) {
  constexpr int K = 2048;
  constexpr int NT = K / 64;   // 32 K-tiles, 16 iterations x 2 tiles
  __shared__ __align__(16) char lds[131072];
  const int tid = threadIdx.x;
  const int l = tid & 63, w = tid >> 6;
  const int wr = w >> 2, wc = w & 3;
  const int l4 = l & 15, lhi = l >> 4;

  constexpr int GX = N / 256;
  const int bid = blockIdx.x;
  const int xcd = bid & 7;
  const int s = bid >> 3;
  const int tx = s % GX;
  const int ty = xcd * 8 + s / GX;
  const size_t rowBase = (size_t)ty * 256;
  const int colBase = tx * 256;

  // ds_read offsets (within a 16KB slot)
  const int swz = (l4 & 7) << 4;
  const int aoffBase = l4 * 128 + ((wr * 64 + lhi * 16) ^ swz);
  const int boffBase = ((wc & 1) * 64 + l4) * 128 + (((wc >> 1) * 64 + lhi * 16) ^ swz);

  // stage source pointers: LDS offset o = c*8192 + tid*16 decodes as
  // lds-row r = o>>7, byte-in-row b0 = o&127; source = inverse-swizzle of b0.
  const char* pAs[2];
  const char* pBs[2];
#pragma unroll
  for (int c = 0; c < 2; ++c) {
    int o = c * 8192 + tid * 16;
    int r = o >> 7, b0 = o & 127;
    int bsw = b0 ^ ((r & 7) << 4);
    int hb = bsw >> 6, cb = bsw & 63;
    pAs[c] = (const char*)A + (rowBase + hb * 128 + r) * (2 * K) + cb;
    pBs[c] = (const char*)BT + ((size_t)colBase + hb * 128 + r) * (2 * K) + cb;
  }
  const int ldso0 = w * 1024;
  const int ldso1 = 8192 + w * 1024;

#define STAGE(srcT, destPar, M, kh)                                          \
  do {                                                                       \
    char* dst_ = lds + (destPar) * 65536 + (kh) * 32768 + (M) * 16384;       \
    const char* s0_ = ((M) ? pBs[0] : pAs[0]) + (srcT) * 128 + (kh) * 64;    \
    const char* s1_ = ((M) ? pBs[1] : pAs[1]) + (srcT) * 128 + (kh) * 64;    \
    gload_lds16(s0_, dst_ + ldso0);                                          \
    gload_lds16(s1_, dst_ + ldso1);                                          \
    asm volatile("" ::: "memory");                                           \
  } while (0)

#define LOADA(q, d, kh)                                                      \
  do {                                                                       \
    const char* sb_ = lds + (d) * 65536 + (kh) * 32768;                      \
    aq[0] = *(const short8*)(sb_ + ((q) * 4 + 0) * 2048 + aoffBase);         \
    aq[1] = *(const short8*)(sb_ + ((q) * 4 + 1) * 2048 + aoffBase);         \
    aq[2] = *(const short8*)(sb_ + ((q) * 4 + 2) * 2048 + aoffBase);         \
    aq[3] = *(const short8*)(sb_ + ((q) * 4 + 3) * 2048 + aoffBase);         \
  } while (0)

#define LOADB(d, kh)                                                         \
  do {                                                                       \
    const char* sb_ = lds + (d) * 65536 + (kh) * 32768 + 16384;              \
    bq[0] = *(const short8*)(sb_ + 0 * 2048 + boffBase);                     \
    bq[1] = *(const short8*)(sb_ + 1 * 2048 + boffBase);                     \
    bq[2] = *(const short8*)(sb_ + 2 * 2048 + boffBase);                     \
    bq[3] = *(const short8*)(sb_ + 3 * 2048 + boffBase);                     \
  } while (0)

#define MF(q)                                                                \
  do {                                                                       \
    _Pragma("unroll") for (int j_ = 0; j_ < 4; ++j_)                         \
        _Pragma("unroll") for (int n_ = 0; n_ < 4; ++n_)                     \
            acc[(q) * 4 + j_][n_] = MFMA(aq[j_], bq[n_], acc[(q) * 4 + j_][n_]); \
  } while (0)

#define BAR()     __builtin_amdgcn_s_barrier()
#define MEMF()    asm volatile("" ::: "memory")
#define VM8()     asm volatile("s_waitcnt vmcnt(8)" ::: "memory")
#define PRIO(x)   __builtin_amdgcn_s_setprio(x)

  f32x4 acc[8][4];
#pragma unroll
  for (int i = 0; i < 8; ++i)
#pragma unroll
    for (int j = 0; j < 4; ++j) acc[i][j] = (f32x4){0.f, 0.f, 0.f, 0.f};

  // prologue: 6 slots, 12 loads; then guard first two slots (vmcnt(8))
  STAGE(0, 0, 0, 0);
  STAGE(0, 0, 1, 0);
  STAGE(0, 0, 0, 1);
  STAGE(0, 0, 1, 1);
  STAGE(1, 1, 0, 0);
  STAGE(1, 1, 1, 0);
  VM8();
  BAR();
  MEMF();

  for (int I = 0; I < NT / 2; ++I) {
    const int o = 2 * I + 1;
    const int e2 = (2 * I + 2 < NT) ? 2 * I + 2 : 0;   // src clamp (uniform counts)
    const int o2 = (2 * I + 3 < NT) ? 2 * I + 3 : 0;
    short8 aq[4], bq[4];
    // ---- p0: tile e, k0, q0 ----  (no barrier at even-phase close)
    LOADB(0, 0);
    LOADA(0, 0, 0);
    STAGE(o, 1, 0, 1);
    PRIO(1); MF(0); PRIO(0);
    MEMF();
    // ---- p1: tile e, k0, q1 ----
    LOADA(1, 0, 0);
    STAGE(o, 1, 1, 1);
    PRIO(1); MF(1); PRIO(0);
    VM8();
    MEMF(); BAR(); MEMF();
    // ---- p2: tile e, k1, q0 ----
    LOADB(0, 1);
    LOADA(0, 0, 1);
    STAGE(e2, 0, 0, 0);
    PRIO(1); MF(0); PRIO(0);
    MEMF();
    // ---- p3: tile e, k1, q1 ----
    LOADA(1, 0, 1);
    STAGE(e2, 0, 1, 0);
    PRIO(1); MF(1); PRIO(0);
    VM8();
    MEMF(); BAR(); MEMF();
    // ---- p4: tile o, k0, q0 ----
    LOADB(1, 0);
    LOADA(0, 1, 0);
    STAGE(e2, 0, 0, 1);
    PRIO(1); MF(0); PRIO(0);
    MEMF();
    // ---- p5: tile o, k0, q1 ----
    LOADA(1, 1, 0);
    STAGE(e2, 0, 1, 1);
    PRIO(1); MF(1); PRIO(0);
    VM8();
    MEMF(); BAR(); MEMF();
    // ---- p6: tile o, k1, q0 ----
    LOADB(1, 1);
    LOADA(0, 1, 1);
    STAGE(o2, 1, 0, 0);
    PRIO(1); MF(0); PRIO(0);
    MEMF();
    // ---- p7: tile o, k1, q1 ----
    LOADA(1, 1, 1);
    STAGE(o2, 1, 1, 0);
    PRIO(1); MF(1); PRIO(0);
    VM8();
    MEMF(); BAR(); MEMF();
  }
  asm volatile("s_waitcnt vmcnt(0)" ::: "memory");

  const int lhi4 = lhi * 4;
  if (MODE == 1) {
    // epilogue: C/D map col=lane&15, row=(lane>>4)*4+reg  [m89/m91 verified]
    int ccv[4];
    float bb[4], wa[4], wb2[4], wc3[4];
#pragma unroll
    for (int n = 0; n < 4; ++n) {
      int cc = colBase + wc * 64 + n * 16 + l4;
      ccv[n] = cc;
      bb[n] = bias[cc];
      wa[n] = wex[cc]; wb2[n] = wex[2048 + cc]; wc3[n] = wex[4096 + cc];
    }
#pragma unroll
    for (int m = 0; m < 8; ++m) {
#pragma unroll
      for (int r = 0; r < 4; ++r) {
        size_t rr = rowBase + wr * 128 + m * 16 + lhi4 + r;
        float f1 = feats[rr], f2 = feats[BATCH + rr], f3 = feats[2 * BATCH + rr];
#pragma unroll
        for (int n = 0; n < 4; ++n) {
          float v = acc[m][n][r] + bb[n] + f1 * wa[n] + f2 * wb2[n] + f3 * wc3[n];
          v = fmaxf(v, 0.f);
          C[rr * N + ccv[n]] = f2bf(v);
        }
      }
    }
  } else {
    // fused head: per-row partial of relu(acc + b2) . Wr over this wave's
    // 64 cols; l4-group shfl reduction (lanes sharing a row); one fp32 store.
    float bb[4], wrv[4];
#pragma unroll
    for (int n = 0; n < 4; ++n) {
      int cc = colBase + wc * 64 + n * 16 + l4;
      bb[n] = bias[cc];
      wrv[n] = Wr[cc];
    }
#pragma unroll
    for (int m = 0; m < 8; ++m) {
#pragma unroll
      for (int r = 0; r < 4; ++r) {
        size_t rr = rowBase + wr * 128 + m * 16 + lhi4 + r;
        float p = 0.f;
#pragma unroll
        for (int n = 0; n < 4; ++n)
          p += fmaxf(acc[m][n][r] + bb[n], 0.f) * wrv[n];
        p += __shfl_xor(p, 1, 64);
        p += __shfl_xor(p, 2, 64);
        p += __shfl_xor(p, 4, 64);
        p += __shfl_xor(p, 8, 64);
        if (l4 == 0) partial[rr * 16 + tx * 4 + wc] = p;
      }
    }
  }
#undef STAGE
#undef LOADA
#undef LOADB
#undef MF
#undef BAR
#undef MEMF
#undef VM8
#undef PRIO
}

// ---------------- final: sum 16 partials per row + sigmoid ----------------
__global__ void __launch_bounds__(256) head2_kernel(const float* __restrict__ partial,
                                                    const float* __restrict__ br,
                                                    float* __restrict__ out) {
  int row = blockIdx.x * 256 + threadIdx.x;
  const float4* p = (const float4*)(partial + (size_t)row * 16);
  float4 a = p[0], b = p[1], c = p[2], d = p[3];
  float s = a.x + a.y + a.z + a.w + b.x + b.y + b.z + b.w +
            c.x + c.y + c.z + c.w + d.x + d.y + d.z + d.w + br[0];
  out[row] = 1.f / (1.f + expf(-s));
}

extern "C" void kernel_launch(void* const* d_in, const int* in_sizes, int n_in,
                              void* d_out, int out_size, void* d_ws, size_t ws_size,
                              hipStream_t stream) {
  const float* h_final = (const float*)d_in[0];
  const float* v_claim = (const float*)d_in[1];
  const float* v_doc   = (const float*)d_in[2];
  const float* W1      = (const float*)d_in[3];
  const float* b1      = (const float*)d_in[4];
  const float* W2      = (const float*)d_in[5];
  const float* b2      = (const float*)d_in[6];
  const float* Wr      = (const float*)d_in[7];
  const float* br      = (const float*)d_in[8];
  float* out = (float*)d_out;

  char* ws = (char*)d_ws;
  ushort* Abf   = (ushort*)ws;                           // 67,108,864 B
  ushort* Hbf   = (ushort*)(ws + 67108864);              // 67,108,864 B
  ushort* W1T   = (ushort*)(ws + 134217728);             //  8,388,608 B
  ushort* W2T   = (ushort*)(ws + 142606336);             //  4,194,304 B
  float*  feats = (float*)(ws + 146800640);              //    196,608 B
  float*  partial = (float*)(ws + 147000320);            // 1,048,576 B

  prep_all<<<18432, 256, 0, stream>>>(h_final, Abf, v_claim, v_doc, feats,
                                      W1, W1T, W2, W2T);

  gemm256<1, DIM><<<(DIM / 256) * (BATCH / 256), 512, 0, stream>>>(
      Abf, W1T, Hbf, feats, W1 + (size_t)2048 * 2048, b1, nullptr, nullptr);
  gemm256<2, DIM2><<<(DIM2 / 256) * (BATCH / 256), 512, 0, stream>>>(
      Hbf, W2T, nullptr, nullptr, nullptr, b2, Wr, partial);

  head2_kernel<<<BATCH / 256, 256, 0, stream>>>(partial, br, out);
}